// Round 4
// baseline (1514.329 us; speedup 1.0000x reference)
//
#include <hip/hip_runtime.h>
#include <stdint.h>

typedef __attribute__((ext_vector_type(8))) short s16x8;
typedef __attribute__((ext_vector_type(4))) float f32x4;

#define MFMA_BF16(a, b, c) __builtin_amdgcn_mfma_f32_16x16x32_bf16((a), (b), (c), 0, 0, 0)

// ---------- helpers ----------

// truncation split: f = hi + lo (hi = bf16-trunc(f), lo = bf16-trunc(f - hi)); packs 2 elems
__device__ __forceinline__ uint32_t pack_hi2(float f0, float f1, float& r0, float& r1) {
  uint32_t b0 = __float_as_uint(f0), b1 = __float_as_uint(f1);
  r0 = f0 - __uint_as_float(b0 & 0xFFFF0000u);
  r1 = f1 - __uint_as_float(b1 & 0xFFFF0000u);
  return (b1 & 0xFFFF0000u) | (b0 >> 16);
}
__device__ __forceinline__ uint32_t pack_lo2(float r0, float r1) {
  return (__float_as_uint(r1) & 0xFFFF0000u) | (__float_as_uint(r0) >> 16);
}
__device__ __forceinline__ uint32_t bfrne(float f) {  // round-to-nearest-even bf16 bits
  uint32_t u = __float_as_uint(f);
  return (u + 0x7FFFu + ((u >> 16) & 1u)) >> 16;
}

// JAX Threefry-2x32, key = (0, 42). Verified bit-exact vs random123 test vector.
__device__ __forceinline__ uint2 threefry2x32_42(uint32_t x0, uint32_t x1) {
  const uint32_t ks0 = 0u, ks1 = 42u, ks2 = 0x1BD11BDAu ^ 42u;
  x0 += ks0; x1 += ks1;
#define TF_R(rot) { x0 += x1; x1 = ((x1 << rot) | (x1 >> (32 - rot))); x1 ^= x0; }
  TF_R(13) TF_R(15) TF_R(26) TF_R(6)   x0 += ks1; x1 += ks2 + 1u;
  TF_R(17) TF_R(29) TF_R(16) TF_R(24)  x0 += ks2; x1 += ks0 + 2u;
  TF_R(13) TF_R(15) TF_R(26) TF_R(6)   x0 += ks0; x1 += ks1 + 3u;
  TF_R(17) TF_R(29) TF_R(16) TF_R(24)  x0 += ks1; x1 += ks2 + 4u;
  TF_R(13) TF_R(15) TF_R(26) TF_R(6)   x0 += ks2; x1 += ks0 + 5u;
#undef TF_R
  return make_uint2(x0, x1);
}

// ============================================================================
// Kernel 1: Y = X @ W   (fp32 in, split-3 bf16 MFMA, fp32 accum)
// Output packed as u32 = (yh_bf16 << 16) | yl_bf16 into d_out (used as scratch)
// ============================================================================
__global__ __launch_bounds__(256, 3) void bilin_gemm1(
    const float* __restrict__ X, const float* __restrict__ W,
    uint32_t* __restrict__ Ypk) {
  __shared__ uint16_t sAh[128][40];
  __shared__ uint16_t sAl[128][40];
  __shared__ uint16_t sBh[128][40];   // W-tile transposed: [n][k]
  __shared__ uint16_t sBl[128][40];

  const int t = threadIdx.x;
  const int lane = t & 63;
  const int wv = t >> 6;
  const int wm = wv >> 1, wn = wv & 1;
  const int lc = lane & 15, lg = lane >> 4;
  const int M0 = blockIdx.y * 128;   // row in [0, 16384)
  const int N0 = blockIdx.x * 128;   // col in [0, 1024)

  const f32x4 fzero = {0.f, 0.f, 0.f, 0.f};
  f32x4 acc[4][4];
#pragma unroll
  for (int i = 0; i < 4; ++i)
#pragma unroll
    for (int j = 0; j < 4; ++j) acc[i][j] = fzero;

  const int ar = t >> 1;            // A stage: row 0..127
  const int ak = (t & 1) * 16;      // A stage: k offset
  const int bc = t & 127;           // B stage: col 0..127
  const int bq = t >> 7;            // B stage: k-half

  const float* aptr = X + (size_t)(M0 + ar) * 1024 + ak;
  const float* bptr = W + (size_t)bq * 16 * 1024 + N0 + bc;

  for (int k0 = 0; k0 < 1024; k0 += 32) {
    // ---- stage A [128][32] (h+l) ----
    {
      const float4* s = (const float4*)(aptr + k0);
#pragma unroll
      for (int q = 0; q < 2; ++q) {
        float4 v0 = s[q * 2 + 0];
        float4 v1 = s[q * 2 + 1];
        float r0, r1, r2, r3, r4, r5, r6, r7;
        uint32_t h0 = pack_hi2(v0.x, v0.y, r0, r1);
        uint32_t h1 = pack_hi2(v0.z, v0.w, r2, r3);
        uint32_t h2 = pack_hi2(v1.x, v1.y, r4, r5);
        uint32_t h3 = pack_hi2(v1.z, v1.w, r6, r7);
        uint32_t l0 = pack_lo2(r0, r1), l1 = pack_lo2(r2, r3);
        uint32_t l2 = pack_lo2(r4, r5), l3 = pack_lo2(r6, r7);
        *(uint4*)&sAh[ar][ak + q * 8] = make_uint4(h0, h1, h2, h3);
        *(uint4*)&sAl[ar][ak + q * 8] = make_uint4(l0, l1, l2, l3);
      }
    }
    // ---- stage B (transposed W) [128 cols][32 k] ----
    {
      float v[16];
#pragma unroll
      for (int i = 0; i < 16; ++i) v[i] = bptr[(size_t)(k0 + i) * 1024];
      float r[16];
      uint32_t h[8], lo[8];
#pragma unroll
      for (int i = 0; i < 8; ++i) h[i] = pack_hi2(v[2 * i], v[2 * i + 1], r[2 * i], r[2 * i + 1]);
#pragma unroll
      for (int i = 0; i < 8; ++i) lo[i] = pack_lo2(r[2 * i], r[2 * i + 1]);
      *(uint4*)&sBh[bc][bq * 16 + 0] = make_uint4(h[0], h[1], h[2], h[3]);
      *(uint4*)&sBh[bc][bq * 16 + 8] = make_uint4(h[4], h[5], h[6], h[7]);
      *(uint4*)&sBl[bc][bq * 16 + 0] = make_uint4(lo[0], lo[1], lo[2], lo[3]);
      *(uint4*)&sBl[bc][bq * 16 + 8] = make_uint4(lo[4], lo[5], lo[6], lo[7]);
    }
    __syncthreads();
    // ---- MFMA: wave subtile 64x64 (4x4 of 16x16), split-3 ----
    s16x8 ah[4], al[4];
#pragma unroll
    for (int mi = 0; mi < 4; ++mi) {
      ah[mi] = *(const s16x8*)&sAh[wm * 64 + mi * 16 + lc][lg * 8];
      al[mi] = *(const s16x8*)&sAl[wm * 64 + mi * 16 + lc][lg * 8];
    }
#pragma unroll
    for (int ni = 0; ni < 4; ++ni) {
      s16x8 bh = *(const s16x8*)&sBh[wn * 64 + ni * 16 + lc][lg * 8];
      s16x8 bl = *(const s16x8*)&sBl[wn * 64 + ni * 16 + lc][lg * 8];
#pragma unroll
      for (int mi = 0; mi < 4; ++mi) {
        acc[mi][ni] = MFMA_BF16(ah[mi], bh, acc[mi][ni]);
        acc[mi][ni] = MFMA_BF16(ah[mi], bl, acc[mi][ni]);
        acc[mi][ni] = MFMA_BF16(al[mi], bh, acc[mi][ni]);
      }
    }
    __syncthreads();
  }
  // ---- epilogue: split y -> (yh|yl) packed u32 ----
#pragma unroll
  for (int mi = 0; mi < 4; ++mi)
#pragma unroll
    for (int ni = 0; ni < 4; ++ni)
#pragma unroll
      for (int r = 0; r < 4; ++r) {
        float y = acc[mi][ni][r];
        uint32_t bb = __float_as_uint(y);
        float rr = y - __uint_as_float(bb & 0xFFFF0000u);
        uint32_t pk = (bb & 0xFFFF0000u) | (__float_as_uint(rr) >> 16);
        int row = M0 + wm * 64 + mi * 16 + lg * 4 + r;
        int col = N0 + wn * 64 + ni * 16 + lc;
        Ypk[(size_t)row * 1024 + col] = pk;
      }
}

// ============================================================================
// Kernel 2: flash attention. 256 threads (4 waves), QBLK=32, KB=128,
// LDS = 35,200 B. upool union: K hi/lo [2][128][40] in QK^T; V^T [64][136] in PV.
// Dropout mask: JAX partitionable threefry (bits = o1^o2, ctr=(0, flat_idx)).
// ============================================================================
__global__ __launch_bounds__(256, 2) void bilin_flash(
    const float* __restrict__ X, float* YO) {
  __shared__ __align__(16) uint16_t upool[10240];   // 20480 B (K pool / vT)
  __shared__ __align__(16) uint16_t qh[32][40];     //  2560 B
  __shared__ __align__(16) uint16_t ql[32][40];     //  2560 B
  __shared__ __align__(16) uint16_t Pl[32][136];    //  8704 B
  __shared__ float red[4][32];                      //   512 B
  __shared__ float mrow[32], lrow[32], frow[32];    //   384 B
  // total 35200 B

  uint16_t (*kp)[40] = (uint16_t(*)[40])upool;      // rows 0..127 hi, 128..255 lo
  uint16_t (*vT)[136] = (uint16_t(*)[136])upool;    // [64 d][128 keys + pad]

  const int t = threadIdx.x;
  const int lane = t & 63;
  const int wv = t >> 6;               // 0..3
  const int lc = lane & 15, lg = lane >> 4;

  const int b = blockIdx.x & 7;        // XCD-affine: batch b -> XCD b
  const int q0 = (blockIdx.x >> 3) * 32;

  const float* Xb = X + (size_t)b * 2048 * 1024;
  const uint32_t* Ypk = (const uint32_t*)YO;

  if (t < 32) { mrow[t] = -1e30f; lrow[t] = 0.0f; }

  const f32x4 fzero = {0.f, 0.f, 0.f, 0.f};
  f32x4 acc_pv[16][2];
#pragma unroll
  for (int dv = 0; dv < 16; ++dv) {
    acc_pv[dv][0] = fzero;
    acc_pv[dv][1] = fzero;
  }

  const int qr = t >> 3;               // Q stage: row 0..31
  const int qi = (t & 7) * 4;          // Q stage: u32-col
  const int kr = t >> 1;               // K stage: key 0..127
  const int kd = (t & 1) * 16;         // K stage: d offset
  const int pvR = (wv >> 1) * 16;      // PV wave row base (0 or 16)
  const int pvC = (wv & 1) * 32;       // PV wave col base (0 or 32)
  const int dcol = t & 127;            // dropout col
  const int drg = (t >> 7) * 16;       // dropout row base (0 or 16)
  const int vdp = t & 31;              // V stage: d-pair 0..31
  const int vkg = t >> 5;              // V stage: key group 0..7

  for (int kb = 0; kb < 16; ++kb) {
    const int kbase = kb * 128;
    __syncthreads();  // protect upool/qh/ql from previous-phase readers

    // ================= QK^T: S[32][128] in regs =================
    f32x4 acc_s[2][2];
#pragma unroll
    for (int i = 0; i < 2; ++i)
#pragma unroll
      for (int j = 0; j < 2; ++j) acc_s[i][j] = fzero;

    for (int dc = 0; dc < 32; ++dc) {
      const int d0 = dc * 32;
      {  // stage Q chunk [32][32] from packed Y (1 uint4 per thread)
        uint4 u = *(const uint4*)&Ypk[(size_t)(b * 2048 + q0 + qr) * 1024 + d0 + qi];
        uint32_t hh0 = (u.y & 0xFFFF0000u) | (u.x >> 16);
        uint32_t hh1 = (u.w & 0xFFFF0000u) | (u.z >> 16);
        uint32_t ll0 = (u.y << 16) | (u.x & 0xFFFFu);
        uint32_t ll1 = (u.w << 16) | (u.z & 0xFFFFu);
        *(uint2*)&qh[qr][qi] = make_uint2(hh0, hh1);
        *(uint2*)&ql[qr][qi] = make_uint2(ll0, ll1);
      }
      {  // stage K chunk [128][32] hi+lo (16 floats per thread)
        const float* src = Xb + (size_t)(kbase + kr) * 1024 + d0 + kd;
        float4 w0 = ((const float4*)src)[0];
        float4 w1 = ((const float4*)src)[1];
        float4 w2 = ((const float4*)src)[2];
        float4 w3 = ((const float4*)src)[3];
        float r[16];
        uint32_t h[8], l[8];
        h[0] = pack_hi2(w0.x, w0.y, r[0], r[1]);
        h[1] = pack_hi2(w0.z, w0.w, r[2], r[3]);
        h[2] = pack_hi2(w1.x, w1.y, r[4], r[5]);
        h[3] = pack_hi2(w1.z, w1.w, r[6], r[7]);
        h[4] = pack_hi2(w2.x, w2.y, r[8], r[9]);
        h[5] = pack_hi2(w2.z, w2.w, r[10], r[11]);
        h[6] = pack_hi2(w3.x, w3.y, r[12], r[13]);
        h[7] = pack_hi2(w3.z, w3.w, r[14], r[15]);
#pragma unroll
        for (int m = 0; m < 8; ++m) l[m] = pack_lo2(r[2 * m], r[2 * m + 1]);
        *(uint4*)&kp[kr][kd] = make_uint4(h[0], h[1], h[2], h[3]);
        *(uint4*)&kp[kr][kd + 8] = make_uint4(h[4], h[5], h[6], h[7]);
        *(uint4*)&kp[128 + kr][kd] = make_uint4(l[0], l[1], l[2], l[3]);
        *(uint4*)&kp[128 + kr][kd + 8] = make_uint4(l[4], l[5], l[6], l[7]);
      }
      __syncthreads();
      s16x8 ah[2], al[2];
#pragma unroll
      for (int mi = 0; mi < 2; ++mi) {
        ah[mi] = *(const s16x8*)&qh[mi * 16 + lc][lg * 8];
        al[mi] = *(const s16x8*)&ql[mi * 16 + lc][lg * 8];
      }
#pragma unroll
      for (int ni = 0; ni < 2; ++ni) {
        s16x8 bh = *(const s16x8*)&kp[wv * 32 + ni * 16 + lc][lg * 8];
        s16x8 bl = *(const s16x8*)&kp[128 + wv * 32 + ni * 16 + lc][lg * 8];
#pragma unroll
        for (int mi = 0; mi < 2; ++mi) {
          acc_s[mi][ni] = MFMA_BF16(ah[mi], bh, acc_s[mi][ni]);
          acc_s[mi][ni] = MFMA_BF16(ah[mi], bl, acc_s[mi][ni]);
          acc_s[mi][ni] = MFMA_BF16(al[mi], bh, acc_s[mi][ni]);
        }
      }
      __syncthreads();
    }

    // ================= online softmax =================
#pragma unroll
    for (int mi = 0; mi < 2; ++mi)
#pragma unroll
      for (int r = 0; r < 4; ++r) {
        float m = fmaxf(acc_s[mi][0][r], acc_s[mi][1][r]);
#pragma unroll
        for (int off = 1; off < 16; off <<= 1) m = fmaxf(m, __shfl_xor(m, off, 64));
        if (lc == 0) red[wv][mi * 16 + lg * 4 + r] = m;
      }
    __syncthreads();
    if (t < 32) {
      float mk = fmaxf(fmaxf(red[0][t], red[1][t]), fmaxf(red[2][t], red[3][t]));
      float mo = mrow[t];
      float mn = fmaxf(mo, mk);
      mrow[t] = mn;
      frow[t] = __expf(mo - mn);
    }
    __syncthreads();
    // exp, P write (bf16 RNE), unmasked row sums
#pragma unroll
    for (int mi = 0; mi < 2; ++mi)
#pragma unroll
      for (int r = 0; r < 4; ++r) {
        const int rl = mi * 16 + lg * 4 + r;
        float mn = mrow[rl];
        float p0 = __expf(acc_s[mi][0][r] - mn);
        float p1 = __expf(acc_s[mi][1][r] - mn);
        Pl[rl][wv * 32 + lc] = (uint16_t)bfrne(p0);
        Pl[rl][wv * 32 + 16 + lc] = (uint16_t)bfrne(p1);
        float s = p0 + p1;
#pragma unroll
        for (int off = 1; off < 16; off <<= 1) s += __shfl_xor(s, off, 64);
        if (lc == 0) red[wv][rl] = s;
      }
    __syncthreads();
    if (t < 32) lrow[t] = lrow[t] * frow[t] + (red[0][t] + red[1][t] + red[2][t] + red[3][t]);
    // dropout: JAX partitionable threefry. flat j = b*2048*2048 + row*2048 + key;
    // ctr = (0, j); bits = o1 ^ o2; u = bitcast(0x3F800000|(bits>>9)) - 1; keep = u < 0.9
    {
      const uint32_t jb = (uint32_t)b * 4194304u + (uint32_t)(q0 + drg) * 2048u +
                          (uint32_t)kbase + (uint32_t)dcol;
#pragma unroll 1
      for (int i = 0; i < 16; ++i) {
        uint32_t j = jb + (uint32_t)i * 2048u;
        uint2 tf = threefry2x32_42(0u, j);
        uint32_t bits = tf.x ^ tf.y;
        float u = __uint_as_float(0x3F800000u | (bits >> 9)) - 1.0f;
        if (!(u < 0.9f)) Pl[drg + i][dcol] = 0;
      }
    }
    __syncthreads();

    // ================= PV =================
    {  // rescale accumulator by exp(m_old - m_new)
      float fr[4];
#pragma unroll
      for (int r = 0; r < 4; ++r) fr[r] = frow[pvR + lg * 4 + r];
#pragma unroll
      for (int dv = 0; dv < 16; ++dv)
#pragma unroll
        for (int n2 = 0; n2 < 2; ++n2)
#pragma unroll
          for (int r = 0; r < 4; ++r) acc_pv[dv][n2][r] *= fr[r];
    }
    s16x8 a[4];
#pragma unroll
    for (int kst = 0; kst < 4; ++kst)
      a[kst] = *(const s16x8*)&Pl[pvR + lc][kst * 32 + lg * 8];

    for (int dv = 0; dv < 16; ++dv) {
      __syncthreads();  // previous vT readers (or K-phase) done
      {  // stage V chunk [128 keys][64 d] transposed into vT (32 floats/thread)
        const float* src = Xb + (size_t)(kbase + vkg * 16) * 1024 + dv * 64 + vdp * 2;
        float2 vv[16];
#pragma unroll
        for (int jj = 0; jj < 16; ++jj) vv[jj] = *(const float2*)(src + (size_t)jj * 1024);
#pragma unroll
        for (int i = 0; i < 2; ++i) {
          uint32_t w[8];
#pragma unroll
          for (int m = 0; m < 8; ++m) {
            float e0 = i ? vv[2 * m].y : vv[2 * m].x;
            float e1 = i ? vv[2 * m + 1].y : vv[2 * m + 1].x;
            w[m] = bfrne(e0) | (bfrne(e1) << 16);
          }
          *(uint4*)&vT[vdp * 2 + i][vkg * 16] = make_uint4(w[0], w[1], w[2], w[3]);
          *(uint4*)&vT[vdp * 2 + i][vkg * 16 + 8] = make_uint4(w[4], w[5], w[6], w[7]);
        }
      }
      __syncthreads();
#pragma unroll
      for (int kst = 0; kst < 4; ++kst) {
        s16x8 b0 = *(const s16x8*)&vT[pvC + lc][kst * 32 + lg * 8];
        s16x8 b1 = *(const s16x8*)&vT[pvC + 16 + lc][kst * 32 + lg * 8];
        acc_pv[dv][0] = MFMA_BF16(a[kst], b0, acc_pv[dv][0]);
        acc_pv[dv][1] = MFMA_BF16(a[kst], b1, acc_pv[dv][1]);
      }
    }
  }  // kb

  // ================= epilogue: out = acc / (l * 0.9) =================
  {
    float inv[4];
#pragma unroll
    for (int r = 0; r < 4; ++r) inv[r] = 1.0f / (lrow[pvR + lg * 4 + r] * 0.9f);
    float* outb = YO + (size_t)b * 2048 * 1024;
#pragma unroll
    for (int dv = 0; dv < 16; ++dv)
#pragma unroll
      for (int n2 = 0; n2 < 2; ++n2)
#pragma unroll
        for (int r = 0; r < 4; ++r) {
          int row = q0 + pvR + lg * 4 + r;
          int col = dv * 64 + pvC + n2 * 16 + lc;
          outb[(size_t)row * 1024 + col] = acc_pv[dv][n2][r] * inv[r];
        }
  }
}

// ============================================================================
extern "C" void kernel_launch(void* const* d_in, const int* in_sizes, int n_in,
                              void* d_out, int out_size, void* d_ws, size_t ws_size,
                              hipStream_t stream) {
  (void)in_sizes; (void)n_in; (void)d_ws; (void)ws_size; (void)out_size;
  const float* X = (const float*)d_in[0];
  const float* W = (const float*)d_in[1];
  // Pass 1: Y = X@W, split-packed bf16 pair per element, stored in d_out.
  bilin_gemm1<<<dim3(8, 128), 256, 0, stream>>>(X, W, (uint32_t*)d_out);
  // Pass 2: flash attention; overwrites d_out rows with final output.
  bilin_flash<<<512, 256, 0, stream>>>(X, (float*)d_out);
}

// Round 5
// 908.049 us; speedup vs baseline: 1.6677x; 1.6677x over previous
//
#include <hip/hip_runtime.h>
#include <stdint.h>

typedef __attribute__((ext_vector_type(8))) short s16x8;
typedef __attribute__((ext_vector_type(4))) float f32x4;

#define MFMA_BF16(a, b, c) __builtin_amdgcn_mfma_f32_16x16x32_bf16((a), (b), (c), 0, 0, 0)

// ---------- helpers ----------
__device__ __forceinline__ uint32_t pack_hi2(float f0, float f1, float& r0, float& r1) {
  uint32_t b0 = __float_as_uint(f0), b1 = __float_as_uint(f1);
  r0 = f0 - __uint_as_float(b0 & 0xFFFF0000u);
  r1 = f1 - __uint_as_float(b1 & 0xFFFF0000u);
  return (b1 & 0xFFFF0000u) | (b0 >> 16);
}
__device__ __forceinline__ uint32_t pack_lo2(float r0, float r1) {
  return (__float_as_uint(r1) & 0xFFFF0000u) | (__float_as_uint(r0) >> 16);
}
__device__ __forceinline__ uint32_t bfrne(float f) {
  uint32_t u = __float_as_uint(f);
  return (u + 0x7FFFu + ((u >> 16) & 1u)) >> 16;
}

// JAX Threefry-2x32, key=(0,42); partitionable mode: bits = o1^o2, ctr=(0, flat_idx)
__device__ __forceinline__ uint2 threefry2x32_42(uint32_t x0, uint32_t x1) {
  const uint32_t ks0 = 0u, ks1 = 42u, ks2 = 0x1BD11BDAu ^ 42u;
  x0 += ks0; x1 += ks1;
#define TF_R(rot) { x0 += x1; x1 = ((x1 << rot) | (x1 >> (32 - rot))); x1 ^= x0; }
  TF_R(13) TF_R(15) TF_R(26) TF_R(6)   x0 += ks1; x1 += ks2 + 1u;
  TF_R(17) TF_R(29) TF_R(16) TF_R(24)  x0 += ks2; x1 += ks0 + 2u;
  TF_R(13) TF_R(15) TF_R(26) TF_R(6)   x0 += ks0; x1 += ks1 + 3u;
  TF_R(17) TF_R(29) TF_R(16) TF_R(24)  x0 += ks1; x1 += ks2 + 4u;
  TF_R(13) TF_R(15) TF_R(26) TF_R(6)   x0 += ks2; x1 += ks0 + 5u;
#undef TF_R
  return make_uint2(x0, x1);
}

// ============================================================================
// Kernel 1: Y = X @ W (unchanged from r4; split-3 bf16 MFMA, packed u32 out)
// ============================================================================
__global__ __launch_bounds__(256, 3) void bilin_gemm1(
    const float* __restrict__ X, const float* __restrict__ W,
    uint32_t* __restrict__ Ypk) {
  __shared__ uint16_t sAh[128][40];
  __shared__ uint16_t sAl[128][40];
  __shared__ uint16_t sBh[128][40];
  __shared__ uint16_t sBl[128][40];

  const int t = threadIdx.x;
  const int lane = t & 63;
  const int wv = t >> 6;
  const int wm = wv >> 1, wn = wv & 1;
  const int lc = lane & 15, lg = lane >> 4;
  const int M0 = blockIdx.y * 128;
  const int N0 = blockIdx.x * 128;

  const f32x4 fzero = {0.f, 0.f, 0.f, 0.f};
  f32x4 acc[4][4];
#pragma unroll
  for (int i = 0; i < 4; ++i)
#pragma unroll
    for (int j = 0; j < 4; ++j) acc[i][j] = fzero;

  const int ar = t >> 1;
  const int ak = (t & 1) * 16;
  const int bc = t & 127;
  const int bq = t >> 7;

  const float* aptr = X + (size_t)(M0 + ar) * 1024 + ak;
  const float* bptr = W + (size_t)bq * 16 * 1024 + N0 + bc;

  for (int k0 = 0; k0 < 1024; k0 += 32) {
    {
      const float4* s = (const float4*)(aptr + k0);
#pragma unroll
      for (int q = 0; q < 2; ++q) {
        float4 v0 = s[q * 2 + 0];
        float4 v1 = s[q * 2 + 1];
        float r0, r1, r2, r3, r4, r5, r6, r7;
        uint32_t h0 = pack_hi2(v0.x, v0.y, r0, r1);
        uint32_t h1 = pack_hi2(v0.z, v0.w, r2, r3);
        uint32_t h2 = pack_hi2(v1.x, v1.y, r4, r5);
        uint32_t h3 = pack_hi2(v1.z, v1.w, r6, r7);
        uint32_t l0 = pack_lo2(r0, r1), l1 = pack_lo2(r2, r3);
        uint32_t l2 = pack_lo2(r4, r5), l3 = pack_lo2(r6, r7);
        *(uint4*)&sAh[ar][ak + q * 8] = make_uint4(h0, h1, h2, h3);
        *(uint4*)&sAl[ar][ak + q * 8] = make_uint4(l0, l1, l2, l3);
      }
    }
    {
      float v[16];
#pragma unroll
      for (int i = 0; i < 16; ++i) v[i] = bptr[(size_t)(k0 + i) * 1024];
      float r[16];
      uint32_t h[8], lo[8];
#pragma unroll
      for (int i = 0; i < 8; ++i) h[i] = pack_hi2(v[2 * i], v[2 * i + 1], r[2 * i], r[2 * i + 1]);
#pragma unroll
      for (int i = 0; i < 8; ++i) lo[i] = pack_lo2(r[2 * i], r[2 * i + 1]);
      *(uint4*)&sBh[bc][bq * 16 + 0] = make_uint4(h[0], h[1], h[2], h[3]);
      *(uint4*)&sBh[bc][bq * 16 + 8] = make_uint4(h[4], h[5], h[6], h[7]);
      *(uint4*)&sBl[bc][bq * 16 + 0] = make_uint4(lo[0], lo[1], lo[2], lo[3]);
      *(uint4*)&sBl[bc][bq * 16 + 8] = make_uint4(lo[4], lo[5], lo[6], lo[7]);
    }
    __syncthreads();
    s16x8 ah[4], al[4];
#pragma unroll
    for (int mi = 0; mi < 4; ++mi) {
      ah[mi] = *(const s16x8*)&sAh[wm * 64 + mi * 16 + lc][lg * 8];
      al[mi] = *(const s16x8*)&sAl[wm * 64 + mi * 16 + lc][lg * 8];
    }
#pragma unroll
    for (int ni = 0; ni < 4; ++ni) {
      s16x8 bh = *(const s16x8*)&sBh[wn * 64 + ni * 16 + lc][lg * 8];
      s16x8 bl = *(const s16x8*)&sBl[wn * 64 + ni * 16 + lc][lg * 8];
#pragma unroll
      for (int mi = 0; mi < 4; ++mi) {
        acc[mi][ni] = MFMA_BF16(ah[mi], bh, acc[mi][ni]);
        acc[mi][ni] = MFMA_BF16(ah[mi], bl, acc[mi][ni]);
        acc[mi][ni] = MFMA_BF16(al[mi], bh, acc[mi][ni]);
      }
    }
    __syncthreads();
  }
#pragma unroll
  for (int mi = 0; mi < 4; ++mi)
#pragma unroll
    for (int ni = 0; ni < 4; ++ni)
#pragma unroll
      for (int r = 0; r < 4; ++r) {
        float y = acc[mi][ni][r];
        uint32_t bb = __float_as_uint(y);
        float rr = y - __uint_as_float(bb & 0xFFFF0000u);
        uint32_t pk = (bb & 0xFFFF0000u) | (__float_as_uint(rr) >> 16);
        int row = M0 + wm * 64 + mi * 16 + lg * 4 + r;
        int col = N0 + wn * 64 + ni * 16 + lc;
        Ypk[(size_t)row * 1024 + col] = pk;
      }
}

// ============================================================================
// Pre-kernels (ws path)
// ============================================================================
__global__ __launch_bounds__(256) void pre_split(const float* __restrict__ X,
    uint16_t* __restrict__ Xh, uint16_t* __restrict__ Xl) {
  size_t i = (size_t)blockIdx.x * 256 + threadIdx.x;
  float4 v = ((const float4*)X)[i];
  uint32_t h0 = bfrne(v.x), h1 = bfrne(v.y), h2 = bfrne(v.z), h3 = bfrne(v.w);
  uint32_t l0 = bfrne(v.x - __uint_as_float(h0 << 16));
  uint32_t l1 = bfrne(v.y - __uint_as_float(h1 << 16));
  uint32_t l2 = bfrne(v.z - __uint_as_float(h2 << 16));
  uint32_t l3 = bfrne(v.w - __uint_as_float(h3 << 16));
  ((uint2*)Xh)[i] = make_uint2(h0 | (h1 << 16), h2 | (h3 << 16));
  ((uint2*)Xl)[i] = make_uint2(l0 | (l1 << 16), l2 | (l3 << 16));
}

__global__ __launch_bounds__(256) void pre_transpose(const float* __restrict__ X,
    uint16_t* __restrict__ XhT) {
  __shared__ uint16_t tile[64][72];
  const int t = threadIdx.x;
  const int b = blockIdx.z;
  const int d0 = blockIdx.x * 64;
  const int k0 = blockIdx.y * 64;
  const int rr = t >> 2;
  const int cq = (t & 3) * 16;
  const float* src = X + (size_t)(b * 2048 + k0 + rr) * 1024 + d0 + cq;
#pragma unroll
  for (int q = 0; q < 4; ++q) {
    float4 v = ((const float4*)src)[q];
    tile[cq + q * 4 + 0][rr] = (uint16_t)bfrne(v.x);
    tile[cq + q * 4 + 1][rr] = (uint16_t)bfrne(v.y);
    tile[cq + q * 4 + 2][rr] = (uint16_t)bfrne(v.z);
    tile[cq + q * 4 + 3][rr] = (uint16_t)bfrne(v.w);
  }
  __syncthreads();
  uint16_t* dst = XhT + (size_t)(b * 1024 + d0 + rr) * 2048 + k0 + cq;
  *(uint4*)dst = *(const uint4*)&tile[rr][cq];
  *(uint4*)(dst + 8) = *(const uint4*)&tile[rr][cq + 8];
}

__global__ __launch_bounds__(256) void maskgen(uint32_t* __restrict__ mw) {
  uint32_t g = blockIdx.x * 256u + threadIdx.x;
  uint2 tf = threefry2x32_42(0u, g);
  uint32_t bits = tf.x ^ tf.y;
  float u = __uint_as_float(0x3F800000u | (bits >> 9)) - 1.0f;
  unsigned long long bal = __ballot(u < 0.9f);
  if ((threadIdx.x & 63) == 0)
    *(uint2*)&mw[g >> 5] = make_uint2((uint32_t)bal, (uint32_t)(bal >> 32));
}

// ============================================================================
// Kernel 2 v2: flash attention. 512 thr (8 waves = 2 row x 4 col), QBLK=32,
// KB=128, double-buffered 1-barrier QK and PV pipelines. LDS 61,312 B.
// ============================================================================
template <bool WS>
__global__ __launch_bounds__(512, 4) void bilin_flash2(
    const float* __restrict__ X, float* __restrict__ YO,
    const uint16_t* __restrict__ Xh, const uint16_t* __restrict__ Xl,
    const uint16_t* __restrict__ XhT, const uint32_t* __restrict__ maskw) {
  __shared__ __align__(16) uint16_t kbuf[2][2][128][40];  // 40960 (also vT region)
  __shared__ __align__(16) uint16_t qbuf[2][2][32][40];   // 10240
  __shared__ __align__(16) uint16_t Pl[32][136];          //  8704
  __shared__ float red[8][16];                            //   512
  __shared__ float mrow[32], lrow[32], frow[32];          //   384
  uint16_t* vbase = &kbuf[0][0][0][0];  // vT[2][64][136] alias = 34816 B

  const int t = threadIdx.x;
  const int lane = t & 63;
  const int wv = t >> 6;
  const int wr = wv >> 2, wc = wv & 3;
  const int lc = lane & 15, lg = lane >> 4;

  const int bid = blockIdx.x;
  const int b = bid & 7;                 // batch -> XCD affinity
  const int q0 = (bid >> 3) * 32;

  const float* Xb = X + (size_t)b * 2048 * 1024;
  const uint16_t* Xhb = WS ? Xh + (size_t)b * 2048 * 1024 : (const uint16_t*)nullptr;
  const uint16_t* Xlb = WS ? Xl + (size_t)b * 2048 * 1024 : (const uint16_t*)nullptr;
  const uint16_t* XhTb = WS ? XhT + (size_t)b * 1024 * 2048 : (const uint16_t*)nullptr;
  const uint32_t* Ypk = (const uint32_t*)YO;

  if (t < 32) { mrow[t] = -1e30f; lrow[t] = 0.0f; }

  const f32x4 fzero = {0.f, 0.f, 0.f, 0.f};
  f32x4 acc_pv[16];
#pragma unroll
  for (int c = 0; c < 16; ++c) acc_pv[c] = fzero;

  const int myrow = wr * 16 + lg * 4;   // + r
  const int qsr = t >> 3;               // (t<256) Q row 0..31
  const int qsc = (t & 7) * 4;          // Q col (elems)
  const int ksk = t >> 2;               // K key 0..127
  const int ksd = (t & 3) * 8;          // K d-offset
  const int vdr = t >> 3;               // WS vT: d-row 0..63
  const int vk16 = (t & 7) * 16;        // WS vT: key offset
  const int vkp = t & 63;               // !WS vT: key pair
  const int vdg = t >> 6;               // !WS vT: d-group

  for (int kb = 0; kb < 16; ++kb) {
    const int kbase = kb * 128;
    __syncthreads();  // kbuf/vT + qbuf reuse guard

    // ---------------- QK^T ----------------
    f32x4 acc_s[2];
    acc_s[0] = fzero; acc_s[1] = fzero;

    uint4 qld;
    uint4 kh, kl;       // WS
    float4 kf0, kf1;    // !WS

    auto load_q = [&](int d0) {
      if (t < 256) qld = *(const uint4*)&Ypk[(size_t)(b * 2048 + q0 + qsr) * 1024 + d0 + qsc];
    };
    auto write_q = [&](int nb) {
      if (t < 256) {
        uint32_t hh0 = (qld.y & 0xFFFF0000u) | (qld.x >> 16);
        uint32_t hh1 = (qld.w & 0xFFFF0000u) | (qld.z >> 16);
        uint32_t ll0 = (qld.y << 16) | (qld.x & 0xFFFFu);
        uint32_t ll1 = (qld.w << 16) | (qld.z & 0xFFFFu);
        *(uint2*)&qbuf[nb][0][qsr][qsc] = make_uint2(hh0, hh1);
        *(uint2*)&qbuf[nb][1][qsr][qsc] = make_uint2(ll0, ll1);
      }
    };
    auto load_k = [&](int d0) {
      if constexpr (WS) {
        kh = *(const uint4*)&Xhb[(size_t)(kbase + ksk) * 1024 + d0 + ksd];
        kl = *(const uint4*)&Xlb[(size_t)(kbase + ksk) * 1024 + d0 + ksd];
      } else {
        const float* s = &Xb[(size_t)(kbase + ksk) * 1024 + d0 + ksd];
        kf0 = ((const float4*)s)[0];
        kf1 = ((const float4*)s)[1];
      }
    };
    auto write_k = [&](int nb) {
      if constexpr (WS) {
        *(uint4*)&kbuf[nb][0][ksk][ksd] = kh;
        *(uint4*)&kbuf[nb][1][ksk][ksd] = kl;
      } else {
        float r0, r1, r2, r3, r4, r5, r6, r7;
        uint32_t h0 = pack_hi2(kf0.x, kf0.y, r0, r1);
        uint32_t h1 = pack_hi2(kf0.z, kf0.w, r2, r3);
        uint32_t h2 = pack_hi2(kf1.x, kf1.y, r4, r5);
        uint32_t h3 = pack_hi2(kf1.z, kf1.w, r6, r7);
        *(uint4*)&kbuf[nb][0][ksk][ksd] = make_uint4(h0, h1, h2, h3);
        *(uint4*)&kbuf[nb][1][ksk][ksd] =
            make_uint4(pack_lo2(r0, r1), pack_lo2(r2, r3), pack_lo2(r4, r5), pack_lo2(r6, r7));
      }
    };

    load_q(0); load_k(0);
    write_q(0); write_k(0);
    __syncthreads();
    for (int dc = 0; dc < 32; ++dc) {
      const int cb = dc & 1;
      if (dc < 31) { load_q((dc + 1) * 32); load_k((dc + 1) * 32); }
      s16x8 ah = *(const s16x8*)&qbuf[cb][0][wr * 16 + lc][lg * 8];
      s16x8 al = *(const s16x8*)&qbuf[cb][1][wr * 16 + lc][lg * 8];
#pragma unroll
      for (int ni = 0; ni < 2; ++ni) {
        s16x8 bh = *(const s16x8*)&kbuf[cb][0][wc * 32 + ni * 16 + lc][lg * 8];
        s16x8 bl = *(const s16x8*)&kbuf[cb][1][wc * 32 + ni * 16 + lc][lg * 8];
        acc_s[ni] = MFMA_BF16(ah, bh, acc_s[ni]);
        acc_s[ni] = MFMA_BF16(ah, bl, acc_s[ni]);
        acc_s[ni] = MFMA_BF16(al, bh, acc_s[ni]);
      }
      if (dc < 31) { write_q(cb ^ 1); write_k(cb ^ 1); __syncthreads(); }
    }

    // ---------------- online softmax (+ fused dropout) ----------------
#pragma unroll
    for (int r = 0; r < 4; ++r) {
      float m = fmaxf(acc_s[0][r], acc_s[1][r]);
      m = fmaxf(m, __shfl_xor(m, 1, 64));
      m = fmaxf(m, __shfl_xor(m, 2, 64));
      m = fmaxf(m, __shfl_xor(m, 4, 64));
      m = fmaxf(m, __shfl_xor(m, 8, 64));
      if (lc == 0) red[wv][lg * 4 + r] = m;
    }
    __syncthreads();
    if (t < 32) {
      int wrr = t >> 4, rr = t & 15;
      float mk = fmaxf(fmaxf(red[wrr * 4 + 0][rr], red[wrr * 4 + 1][rr]),
                       fmaxf(red[wrr * 4 + 2][rr], red[wrr * 4 + 3][rr]));
      float mo = mrow[t], mn = fmaxf(mo, mk);
      mrow[t] = mn;
      frow[t] = __expf(mo - mn);
    }
    __syncthreads();
    uint32_t mwd[4];
    if constexpr (WS) {
#pragma unroll
      for (int r = 0; r < 4; ++r)
        mwd[r] = maskw[((uint32_t)b * 4194304u + (uint32_t)(q0 + myrow + r) * 2048u +
                        (uint32_t)(kbase + wc * 32)) >> 5];
    }
#pragma unroll
    for (int r = 0; r < 4; ++r) {
      const int row = myrow + r;
      const float mn = mrow[row];
      float p0 = __expf(acc_s[0][r] - mn);
      float p1 = __expf(acc_s[1][r] - mn);
      float s = p0 + p1;
      s += __shfl_xor(s, 1, 64);
      s += __shfl_xor(s, 2, 64);
      s += __shfl_xor(s, 4, 64);
      s += __shfl_xor(s, 8, 64);
      if (lc == 0) red[wv][lg * 4 + r] = s;
      bool k0, k1;
      if constexpr (WS) {
        k0 = (mwd[r] >> lc) & 1u;
        k1 = (mwd[r] >> (16 + lc)) & 1u;
      } else {
        uint32_t jr = (uint32_t)b * 4194304u + (uint32_t)(q0 + row) * 2048u +
                      (uint32_t)(kbase + wc * 32 + lc);
        uint2 t0 = threefry2x32_42(0u, jr);
        uint2 t1 = threefry2x32_42(0u, jr + 16u);
        k0 = (__uint_as_float(0x3F800000u | ((t0.x ^ t0.y) >> 9)) - 1.0f) < 0.9f;
        k1 = (__uint_as_float(0x3F800000u | ((t1.x ^ t1.y) >> 9)) - 1.0f) < 0.9f;
      }
      Pl[row][wc * 32 + lc] = k0 ? (uint16_t)bfrne(p0) : (uint16_t)0;
      Pl[row][wc * 32 + 16 + lc] = k1 ? (uint16_t)bfrne(p1) : (uint16_t)0;
    }
    __syncthreads();
    if (t < 32) {
      int wrr = t >> 4, rr = t & 15;
      float s = red[wrr * 4 + 0][rr] + red[wrr * 4 + 1][rr] +
                red[wrr * 4 + 2][rr] + red[wrr * 4 + 3][rr];
      lrow[t] = lrow[t] * frow[t] + s;
    }

    // ---------------- PV ----------------
    {
      float fr[4];
#pragma unroll
      for (int r = 0; r < 4; ++r) fr[r] = frow[myrow + r];
#pragma unroll
      for (int c = 0; c < 16; ++c)
#pragma unroll
        for (int r = 0; r < 4; ++r) acc_pv[c][r] *= fr[r];
    }
    s16x8 ap[4];
#pragma unroll
    for (int kst = 0; kst < 4; ++kst)
      ap[kst] = *(const s16x8*)&Pl[wr * 16 + lc][kst * 32 + lg * 8];

    uint4 va, vb2;
    float4 vf0, vf1, vf2, vf3;
    auto load_v = [&](int c) {
      if constexpr (WS) {
        const uint16_t* s = &XhTb[(size_t)(c * 64 + vdr) * 2048 + kbase + vk16];
        va = ((const uint4*)s)[0];
        vb2 = ((const uint4*)s)[1];
      } else {
        const float* s0 = &Xb[(size_t)(kbase + vkp * 2) * 1024 + c * 64 + vdg * 8];
        vf0 = ((const float4*)s0)[0];
        vf1 = ((const float4*)s0)[1];
        vf2 = ((const float4*)(s0 + 1024))[0];
        vf3 = ((const float4*)(s0 + 1024))[1];
      }
    };
    auto write_v = [&](int nb) {
      uint16_t* vt = vbase + nb * (64 * 136);
      if constexpr (WS) {
        *(uint4*)&vt[vdr * 136 + vk16] = va;
        *(uint4*)&vt[vdr * 136 + vk16 + 8] = vb2;
      } else {
        uint32_t w0 = bfrne(vf0.x) | (bfrne(vf2.x) << 16);
        uint32_t w1 = bfrne(vf0.y) | (bfrne(vf2.y) << 16);
        uint32_t w2 = bfrne(vf0.z) | (bfrne(vf2.z) << 16);
        uint32_t w3 = bfrne(vf0.w) | (bfrne(vf2.w) << 16);
        uint32_t w4 = bfrne(vf1.x) | (bfrne(vf3.x) << 16);
        uint32_t w5 = bfrne(vf1.y) | (bfrne(vf3.y) << 16);
        uint32_t w6 = bfrne(vf1.z) | (bfrne(vf3.z) << 16);
        uint32_t w7 = bfrne(vf1.w) | (bfrne(vf3.w) << 16);
        *(uint32_t*)&vt[(vdg * 8 + 0) * 136 + vkp * 2] = w0;
        *(uint32_t*)&vt[(vdg * 8 + 1) * 136 + vkp * 2] = w1;
        *(uint32_t*)&vt[(vdg * 8 + 2) * 136 + vkp * 2] = w2;
        *(uint32_t*)&vt[(vdg * 8 + 3) * 136 + vkp * 2] = w3;
        *(uint32_t*)&vt[(vdg * 8 + 4) * 136 + vkp * 2] = w4;
        *(uint32_t*)&vt[(vdg * 8 + 5) * 136 + vkp * 2] = w5;
        *(uint32_t*)&vt[(vdg * 8 + 6) * 136 + vkp * 2] = w6;
        *(uint32_t*)&vt[(vdg * 8 + 7) * 136 + vkp * 2] = w7;
      }
    };

    load_v(0); write_v(0);
    __syncthreads();
#pragma unroll
    for (int c = 0; c < 16; ++c) {
      const int cb = c & 1;
      if (c < 15) load_v(c + 1);
      const uint16_t* vt = vbase + cb * (64 * 136);
#pragma unroll
      for (int kst = 0; kst < 4; ++kst) {
        s16x8 bf = *(const s16x8*)&vt[(wc * 16 + lc) * 136 + kst * 32 + lg * 8];
        acc_pv[c] = MFMA_BF16(ap[kst], bf, acc_pv[c]);
      }
      if (c < 15) { write_v(cb ^ 1); __syncthreads(); }
    }
  }  // kb

  // ---------------- epilogue: out = acc / (l * 0.9) ----------------
  __syncthreads();
  float inv[4];
#pragma unroll
  for (int r = 0; r < 4; ++r) inv[r] = 1.0f / (lrow[myrow + r] * 0.9f);
  float* outb = YO + (size_t)b * 2048 * 1024;
#pragma unroll
  for (int c = 0; c < 16; ++c)
#pragma unroll
    for (int r = 0; r < 4; ++r)
      outb[(size_t)(q0 + myrow + r) * 1024 + c * 64 + wc * 16 + lc] =
          acc_pv[c][r] * inv[r];
}

// ============================================================================
extern "C" void kernel_launch(void* const* d_in, const int* in_sizes, int n_in,
                              void* d_out, int out_size, void* d_ws, size_t ws_size,
                              hipStream_t stream) {
  (void)in_sizes; (void)n_in; (void)out_size;
  const float* X = (const float*)d_in[0];
  const float* W = (const float*)d_in[1];
  const bool usews = ws_size >= 104857600ULL;  // XhT+Xh+Xl (96MB) + mask (4MB)

  bilin_gemm1<<<dim3(8, 128), 256, 0, stream>>>(X, W, (uint32_t*)d_out);

  if (usews) {
    uint16_t* XhT = (uint16_t*)d_ws;
    uint16_t* Xh = (uint16_t*)((char*)d_ws + 33554432);
    uint16_t* Xl = (uint16_t*)((char*)d_ws + 67108864);
    uint32_t* mw = (uint32_t*)((char*)d_ws + 100663296);
    pre_split<<<16384, 256, 0, stream>>>(X, Xh, Xl);
    pre_transpose<<<dim3(16, 32, 8), 256, 0, stream>>>(X, XhT);
    maskgen<<<131072, 256, 0, stream>>>(mw);
    bilin_flash2<true><<<512, 512, 0, stream>>>(X, (float*)d_out, Xh, Xl, XhT, mw);
  } else {
    bilin_flash2<false><<<512, 512, 0, stream>>>(X, (float*)d_out,
                                                 nullptr, nullptr, nullptr, nullptr);
  }
}